// Round 22
// baseline (738.176 us; speedup 1.0000x reference)
//
#include <hip/hip_runtime.h>

typedef __attribute__((ext_vector_type(8))) short short8;
typedef __attribute__((ext_vector_type(4))) short short4v;
typedef __attribute__((ext_vector_type(4))) float f32x4;

__device__ inline short f2bf(float f) {
    union { float f; unsigned u; } v; v.f = f;
    unsigned r = v.u + 0x7fffu + ((v.u >> 16) & 1u);
    return (short)(r >> 16);
}

__device__ __forceinline__ void gload16(const short* g, short* l) {
    __builtin_amdgcn_global_load_lds(
        (const __attribute__((address_space(1))) unsigned int*)g,
        (__attribute__((address_space(3))) unsigned int*)l, 16, 0, 0);
}

// ---------------- elementwise f32 -> bf16 (16B/lane both ways) ----------------
__global__ __launch_bounds__(256) void cvt_f32_to_bf16(const float* __restrict__ in,
                                                       short* __restrict__ out, int n8) {
    int i = blockIdx.x * 256 + threadIdx.x;
    if (i >= n8) return;
    float4 a = ((const float4*)in)[i * 2];
    float4 b = ((const float4*)in)[i * 2 + 1];
    short8 o;
    o[0] = f2bf(a.x); o[1] = f2bf(a.y); o[2] = f2bf(a.z); o[3] = f2bf(a.w);
    o[4] = f2bf(b.x); o[5] = f2bf(b.y); o[6] = f2bf(b.z); o[7] = f2bf(b.w);
    ((short8*)out)[i] = o;
}

// ---------------- tiled transpose (R x C) f32 -> bf16 (C x R), vectorized ----------------
__global__ __launch_bounds__(256) void transpose_to_bf16(const float* __restrict__ in,
                                                         short* __restrict__ out,
                                                         int R, int C) {
    __shared__ short tile[64][68];
    int r0 = blockIdx.x * 64, c0 = blockIdx.y * 64;
    int tid = threadIdx.x;
#pragma unroll
    for (int i = 0; i < 4; i++) {
        int k = i * 256 + tid;
        int r = k >> 4, c4 = k & 15;
        float4 v = *(const float4*)(in + (size_t)(r0 + r) * C + c0 + c4 * 4);
        short4v s;
        s[0] = f2bf(v.x); s[1] = f2bf(v.y); s[2] = f2bf(v.z); s[3] = f2bf(v.w);
        *(short4v*)&tile[r][c4 * 4] = s;
    }
    __syncthreads();
#pragma unroll
    for (int i = 0; i < 2; i++) {
        int k = i * 256 + tid;
        int c = k >> 3, r8 = k & 7;
        short8 o;
#pragma unroll
        for (int j = 0; j < 8; j++) o[j] = tile[r8 * 8 + j][c];
        *(short8*)(out + (size_t)(c0 + c) * R + r0 + r8 * 8) = o;
    }
}

// ======== bf16 GEMM 256x256, BK=32, 4-buf depth-3, persistent (r21, unchanged) ====
template <int EPI>
__global__ __launch_bounds__(512) void gemm256(const short* __restrict__ A,
                                               const short* __restrict__ Bt,
                                               int M, int N, int K,
                                               short* __restrict__ O0, short* __restrict__ O1,
                                               short* __restrict__ O2, float* __restrict__ OF,
                                               float qscale, int gpb) {
    __shared__ short As[4][256 * 32];
    __shared__ short Bs[4][256 * 32];
    int tid = threadIdx.x, lane = tid & 63, wid = tid >> 6;
    int wr = wid >> 2, wc = wid & 3;
    int mtn = M >> 8;
    int band = mtn >> 3;
    int bid = blockIdx.x;
    int xcd = bid & 7;
    int kkstep = gridDim.x >> 3;
    int t15 = lane & 15, t4 = lane >> 4;
    int NT = K >> 5;
    int sg = (lane & 3) ^ ((lane >> 3) & 3);
    int srw = lane >> 2;
    int ce = t4 ^ ((t15 >> 1) & 3);

    for (int g = 0; g < gpb; g++) {
        int kk = (bid >> 3) + g * kkstep;
        int nt = kk / band, gmr = kk % band;
        int mt = xcd * band + gmr;
        int row0 = mt << 8, col0 = nt << 8;

        f32x4 acc[8][4];
#pragma unroll
        for (int m = 0; m < 8; m++)
#pragma unroll
            for (int n = 0; n < 4; n++) acc[m][n] = (f32x4){0.f, 0.f, 0.f, 0.f};

        auto stageA = [&](int t) {
            if (t >= NT) return;
            int kb = t << 5;
            short* dst = &As[t & 3][0];
#pragma unroll
            for (int i = 0; i < 2; i++) {
                int seg = wid * 2 + i;
                int row = seg * 16 + srw;
                gload16(A + (size_t)(row0 + row) * K + kb + sg * 8, dst + seg * 512);
            }
        };
        auto stageB = [&](int t) {
            if (t >= NT) return;
            int kb = t << 5;
            short* dst = &Bs[t & 3][0];
#pragma unroll
            for (int i = 0; i < 2; i++) {
                int seg = wid * 2 + i;
                int row = seg * 16 + srw;
                gload16(Bt + (size_t)(col0 + row) * K + kb + sg * 8, dst + seg * 512);
            }
        };

        stageA(0); stageB(0);
        stageA(1); stageB(1);
        stageA(2); stageB(2);
        asm volatile("s_waitcnt vmcnt(8)" ::: "memory");
        asm volatile("s_barrier" ::: "memory");

        for (int t = 0; t < NT; t++) {
            int bufi = t & 3;
            short8 af[8], bf[4];
#pragma unroll
            for (int m = 0; m < 8; m++) {
                int row = wr * 128 + m * 16 + t15;
                af[m] = *(short8*)(&As[bufi][row * 32 + ce * 8]);
            }
#pragma unroll
            for (int n = 0; n < 4; n++) {
                int row = wc * 64 + n * 16 + t15;
                bf[n] = *(short8*)(&Bs[bufi][row * 32 + ce * 8]);
            }
            stageA(t + 3); stageB(t + 3);

            __builtin_amdgcn_s_setprio(1);
#pragma unroll
            for (int m = 0; m < 8; m++)
#pragma unroll
                for (int n = 0; n < 4; n++)
                    acc[m][n] = __builtin_amdgcn_mfma_f32_16x16x32_bf16(af[m], bf[n], acc[m][n], 0, 0, 0);
            __builtin_amdgcn_s_setprio(0);

            if (t + 3 < NT)       asm volatile("s_waitcnt vmcnt(8)" ::: "memory");
            else if (t + 3 == NT) asm volatile("s_waitcnt vmcnt(4)" ::: "memory");
            else                  asm volatile("s_waitcnt vmcnt(0)" ::: "memory");
            asm volatile("s_barrier" ::: "memory");
        }

#pragma unroll
        for (int m = 0; m < 8; m++) {
#pragma unroll
            for (int n = 0; n < 4; n++) {
#pragma unroll
                for (int r = 0; r < 4; r++) {
                    float v = acc[m][n][r];
                    int gm2 = row0 + wr * 128 + m * 16 + t4 * 4 + r;
                    int gn = col0 + wc * 64 + n * 16 + t15;
                    if (EPI == 0) {
                        int part = gn >> 11, within = gn & 2047;
                        int h = within >> 7, dk = within & 127;
                        int bb = gm2 >> 11, s = gm2 & 2047;
                        int z = bb * 16 + h;
                        if (part == 0) O0[((size_t)z * 2048 + s) * 128 + dk] = f2bf(v * qscale);
                        else if (part == 1) O1[((size_t)z * 2048 + s) * 128 + dk] = f2bf(v);
                        else O2[((size_t)z * 128 + dk) * 2048 + s] = f2bf(v);  // V transposed
                    } else {
                        OF[(size_t)gm2 * N + gn] = v;
                    }
                }
            }
        }
    }
}

// ---------------- causal flash attention: 32 q-rows/wave (2 q-halves share K/V reads) ----
// Block = 256 q-rows (panel p), 8 waves x 32 rows. Each kf/vf ds_read feeds TWO
// MFMAs (one per q-half) -> FLOP/LDS-byte 15.4 -> 58 (attn was ~80% LDS-read-bound).
// grid (z=64, p=8): linear id = z + 64p -> XCD = z%8: all panels of a z on one XCD
// (K/V L2-resident), all XCDs get identical panel mix. Counted-vmcnt barriers (r20).
// active flag shared by halves: t*64 - q0w is a multiple of 32, so both halves
// activate together.
__global__ __launch_bounds__(512, 4) void attn_fwd(const short* __restrict__ Q,
                                                   const short* __restrict__ Kb,
                                                   const short* __restrict__ Vt,
                                                   short* __restrict__ O) {
    __shared__ short Kls[2][64 * 128];
    __shared__ short Vls[128 * 64];
    __shared__ __align__(16) short Pls[8][32 * 64];
    int tid = threadIdx.x, lane = tid & 63, wid = tid >> 6;
    int z = blockIdx.x, p = blockIdx.y;
    int t15 = lane & 15, t4 = lane >> 4;
    const short* Qh = Q + (size_t)z * 2048 * 128;
    const short* Kh = Kb + (size_t)z * 2048 * 128;
    const short* Vh = Vt + (size_t)z * 128 * 2048;
    int q0w = p * 256 + wid * 32;

    short8 qf[2][4];
#pragma unroll
    for (int h = 0; h < 2; h++) {
        const short* qrow = Qh + (size_t)(q0w + h * 16 + t15) * 128;
#pragma unroll
        for (int s = 0; s < 4; s++) qf[h][s] = *(const short8*)(qrow + s * 32 + t4 * 8);
    }

    f32x4 o0[8], o1[8];
#pragma unroll
    for (int st = 0; st < 8; st++) {
        o0[st] = (f32x4){0.f, 0.f, 0.f, 0.f};
        o1[st] = (f32x4){0.f, 0.f, 0.f, 0.f};
    }
    float m_s[2] = {-1e30f, -1e30f}, l_s[2] = {0.f, 0.f};

    auto stageK = [&](int t, int buf) {
#pragma unroll
        for (int i = 0; i < 2; i++) {
            int seg = wid * 2 + i;
            int row = seg * 4 + t4;
            int kl = (lane & 15) ^ (row & 7);
            gload16(Kh + (size_t)(t * 64 + row) * 128 + kl * 8, &Kls[buf][seg * 512]);
        }
    };
    auto stageV = [&](int t) {
#pragma unroll
        for (int i = 0; i < 2; i++) {
            int seg = wid * 2 + i;
            int row = seg * 8 + (lane >> 3);
            int kl = (lane & 7) ^ (row & 7);
            gload16(Vh + (size_t)row * 2048 + t * 64 + kl * 8, &Vls[seg * 512]);
        }
    };

    int nt = 4 * p + 4;
    stageK(0, 0);
    __syncthreads();

    int t15l = t15 & 7;

    for (int t = 0; t < nt; t++) {
        int buf = t & 1;
        stageV(t);
        if (t + 1 < nt) stageK(t + 1, buf ^ 1);
        bool active = (t * 64 <= q0w + 15);

        if (active) {
            f32x4 sc0[4], sc1[4];
#pragma unroll
            for (int c = 0; c < 4; c++) {
                sc0[c] = (f32x4){0.f, 0.f, 0.f, 0.f};
                sc1[c] = (f32x4){0.f, 0.f, 0.f, 0.f};
            }
#pragma unroll
            for (int c = 0; c < 4; c++) {
#pragma unroll
                for (int s = 0; s < 4; s++) {
                    int row = c * 16 + t15;
                    int ck = (s * 4 + t4) ^ (row & 7);
                    short8 kf = *(short8*)(&Kls[buf][row * 128 + ck * 8]);
                    sc0[c] = __builtin_amdgcn_mfma_f32_16x16x32_bf16(kf, qf[0][s], sc0[c], 0, 0, 0);
                    sc1[c] = __builtin_amdgcn_mfma_f32_16x16x32_bf16(kf, qf[1][s], sc1[c], 0, 0, 0);
                }
            }

            bool diag = (t * 64 + 63 > q0w);

            // ---- half 0 ----
            {
                f32x4* sc = sc0;
                if (diag) {
                    int qq = q0w + t15;
#pragma unroll
                    for (int c = 0; c < 4; c++)
#pragma unroll
                        for (int r = 0; r < 4; r++) {
                            int kv = t * 64 + c * 16 + t4 * 4 + r;
                            if (kv > qq) sc[c][r] = -1e30f;
                        }
                }
                float tm = fmaxf(fmaxf(fmaxf(sc[0][0], sc[0][1]), fmaxf(sc[0][2], sc[0][3])),
                                 fmaxf(fmaxf(sc[1][0], sc[1][1]), fmaxf(sc[1][2], sc[1][3])));
                tm = fmaxf(tm, fmaxf(fmaxf(fmaxf(sc[2][0], sc[2][1]), fmaxf(sc[2][2], sc[2][3])),
                                     fmaxf(fmaxf(sc[3][0], sc[3][1]), fmaxf(sc[3][2], sc[3][3]))));
                bool need = (tm > m_s[0] + 8.f);
                if (__any(need)) {
                    tm = fmaxf(tm, __shfl_xor(tm, 16));
                    tm = fmaxf(tm, __shfl_xor(tm, 32));
                    float mn = fmaxf(m_s[0], tm);
                    float scf = exp2f(m_s[0] - mn);
                    m_s[0] = mn;
                    l_s[0] *= scf;
                    float sr0 = __shfl(scf, t4 * 4 + 0);
                    float sr1 = __shfl(scf, t4 * 4 + 1);
                    float sr2 = __shfl(scf, t4 * 4 + 2);
                    float sr3 = __shfl(scf, t4 * 4 + 3);
#pragma unroll
                    for (int st = 0; st < 8; st++) {
                        o0[st][0] *= sr0; o0[st][1] *= sr1;
                        o0[st][2] *= sr2; o0[st][3] *= sr3;
                    }
                }
#pragma unroll
                for (int c = 0; c < 4; c++) {
                    float p0 = exp2f(sc[c][0] - m_s[0]);
                    float p1 = exp2f(sc[c][1] - m_s[0]);
                    float p2 = exp2f(sc[c][2] - m_s[0]);
                    float p3 = exp2f(sc[c][3] - m_s[0]);
                    l_s[0] += (p0 + p1) + (p2 + p3);
                    unsigned u0, u1;
                    asm("v_cvt_pk_bf16_f32 %0, %1, %2" : "=v"(u0) : "v"(p0), "v"(p1));
                    asm("v_cvt_pk_bf16_f32 %0, %1, %2" : "=v"(u1) : "v"(p2), "v"(p3));
                    int ch = (c * 2 + (t4 >> 1)) ^ t15l;
                    uint2 uu; uu.x = u0; uu.y = u1;
                    *(uint2*)((char*)&Pls[wid][0] + t15 * 128 + ch * 16 + (t4 & 1) * 8) = uu;
                }
            }
            // ---- half 1 ----
            {
                f32x4* sc = sc1;
                if (diag) {
                    int qq = q0w + 16 + t15;
#pragma unroll
                    for (int c = 0; c < 4; c++)
#pragma unroll
                        for (int r = 0; r < 4; r++) {
                            int kv = t * 64 + c * 16 + t4 * 4 + r;
                            if (kv > qq) sc[c][r] = -1e30f;
                        }
                }
                float tm = fmaxf(fmaxf(fmaxf(sc[0][0], sc[0][1]), fmaxf(sc[0][2], sc[0][3])),
                                 fmaxf(fmaxf(sc[1][0], sc[1][1]), fmaxf(sc[1][2], sc[1][3])));
                tm = fmaxf(tm, fmaxf(fmaxf(fmaxf(sc[2][0], sc[2][1]), fmaxf(sc[2][2], sc[2][3])),
                                     fmaxf(fmaxf(sc[3][0], sc[3][1]), fmaxf(sc[3][2], sc[3][3]))));
                bool need = (tm > m_s[1] + 8.f);
                if (__any(need)) {
                    tm = fmaxf(tm, __shfl_xor(tm, 16));
                    tm = fmaxf(tm, __shfl_xor(tm, 32));
                    float mn = fmaxf(m_s[1], tm);
                    float scf = exp2f(m_s[1] - mn);
                    m_s[1] = mn;
                    l_s[1] *= scf;
                    float sr0 = __shfl(scf, t4 * 4 + 0);
                    float sr1 = __shfl(scf, t4 * 4 + 1);
                    float sr2 = __shfl(scf, t4 * 4 + 2);
                    float sr3 = __shfl(scf, t4 * 4 + 3);
#pragma unroll
                    for (int st = 0; st < 8; st++) {
                        o1[st][0] *= sr0; o1[st][1] *= sr1;
                        o1[st][2] *= sr2; o1[st][3] *= sr3;
                    }
                }
#pragma unroll
                for (int c = 0; c < 4; c++) {
                    float p0 = exp2f(sc[c][0] - m_s[1]);
                    float p1 = exp2f(sc[c][1] - m_s[1]);
                    float p2 = exp2f(sc[c][2] - m_s[1]);
                    float p3 = exp2f(sc[c][3] - m_s[1]);
                    l_s[1] += (p0 + p1) + (p2 + p3);
                    unsigned u0, u1;
                    asm("v_cvt_pk_bf16_f32 %0, %1, %2" : "=v"(u0) : "v"(p0), "v"(p1));
                    asm("v_cvt_pk_bf16_f32 %0, %1, %2" : "=v"(u1) : "v"(p2), "v"(p3));
                    int ch = (c * 2 + (t4 >> 1)) ^ t15l;
                    uint2 uu; uu.x = u0; uu.y = u1;
                    *(uint2*)((char*)&Pls[wid][0] + (16 + t15) * 128 + ch * 16 + (t4 & 1) * 8) = uu;
                }
            }
        }

        if (t + 1 < nt) asm volatile("s_waitcnt vmcnt(2)" ::: "memory");
        else            asm volatile("s_waitcnt vmcnt(0)" ::: "memory");
        __builtin_amdgcn_s_barrier();

        if (active) {
            short8 pa0[2], pa1[2];
#pragma unroll
            for (int s2 = 0; s2 < 2; s2++) {
                int ch2 = (s2 * 4 + t4) ^ t15l;
                pa0[s2] = *(short8*)((char*)&Pls[wid][0] + t15 * 128 + ch2 * 16);
                pa1[s2] = *(short8*)((char*)&Pls[wid][0] + (16 + t15) * 128 + ch2 * 16);
            }
#pragma unroll
            for (int st = 0; st < 8; st++) {
#pragma unroll
                for (int s2 = 0; s2 < 2; s2++) {
                    int row = st * 16 + t15;
                    int ck = (s2 * 4 + t4) ^ (row & 7);
                    short8 vf = *(short8*)(&Vls[row * 64 + ck * 8]);
                    o0[st] = __builtin_amdgcn_mfma_f32_16x16x32_bf16(pa0[s2], vf, o0[st], 0, 0, 0);
                    o1[st] = __builtin_amdgcn_mfma_f32_16x16x32_bf16(pa1[s2], vf, o1[st], 0, 0, 0);
                }
            }
        }

        asm volatile("s_waitcnt vmcnt(0)" ::: "memory");
        __builtin_amdgcn_s_barrier();
    }

    int b = z >> 4, hh = z & 15;
#pragma unroll
    for (int h = 0; h < 2; h++) {
        float ls = l_s[h];
        ls += __shfl_xor(ls, 16);
        ls += __shfl_xor(ls, 32);
        float lr0 = __shfl(ls, t4 * 4 + 0);
        float lr1 = __shfl(ls, t4 * 4 + 1);
        float lr2 = __shfl(ls, t4 * 4 + 2);
        float lr3 = __shfl(ls, t4 * 4 + 3);
        float lr[4] = {lr0, lr1, lr2, lr3};
        f32x4* o = (h == 0) ? o0 : o1;
#pragma unroll
        for (int st = 0; st < 8; st++)
#pragma unroll
            for (int r = 0; r < 4; r++) {
                int s = q0w + h * 16 + t4 * 4 + r;
                float val = o[st][r] / lr[r];
                O[((size_t)b * 2048 + s) * 2048 + hh * 128 + st * 16 + t15] = f2bf(val);
            }
    }
}

extern "C" void kernel_launch(void* const* d_in, const int* in_sizes, int n_in,
                              void* d_out, int out_size, void* d_ws, size_t ws_size,
                              hipStream_t stream) {
    const float* x = (const float*)d_in[0];      // (4,2048,2048)
    const float* Wqkv = (const float*)d_in[1];   // (2048,6144)
    const float* Wo = (const float*)d_in[2];     // (2048,2048)

    const int B = 4, S = 2048, D = 2048, DK = 128;
    const int M = B * S;          // 8192
    const int N1 = 3 * D;         // 6144
    (void)in_sizes; (void)n_in; (void)out_size; (void)ws_size;

    char* ws = (char*)d_ws;
    size_t off = 0;
    short* x_bf = (short*)(ws + off);   off += (size_t)M * D * 2;
    short* wqkv_t = (short*)(ws + off); off += (size_t)N1 * D * 2;
    short* wo_t = (short*)(ws + off);   off += (size_t)D * D * 2;
    short* Qb = (short*)(ws + off);     off += (size_t)64 * S * DK * 2;
    short* Kb = (short*)(ws + off);     off += (size_t)64 * S * DK * 2;
    short* Vt = (short*)(ws + off);     off += (size_t)64 * S * DK * 2;
    short* Ob = (short*)(ws + off);     off += (size_t)M * D * 2;

    // 1. x -> bf16 (16B/lane)
    cvt_f32_to_bf16<<<(M * D / 8 + 255) / 256, 256, 0, stream>>>(x, x_bf, M * D / 8);
    // 2. Wqkv^T -> bf16 (N1 x D), vectorized
    transpose_to_bf16<<<dim3(D / 64, N1 / 64, 1), 256, 0, stream>>>(Wqkv, wqkv_t, D, N1);
    // 3. Wo^T -> bf16 (D x D), vectorized
    transpose_to_bf16<<<dim3(D / 64, D / 64, 1), 256, 0, stream>>>(Wo, wo_t, D, D);
    // 4. GEMM1: qkv = x @ Wqkv -> Q(scaled 1/(sqrt(128)ln2))/K/V^T  (persistent, 256 x 3)
    gemm256<0><<<256, 512, 0, stream>>>(
        x_bf, wqkv_t, M, N1, D, Qb, Kb, Vt, nullptr, 0.12751743553366927f, 3);
    // 5. attention (256-row panels, 32 q-rows/wave, shared K/V reads)
    attn_fwd<<<dim3(64, 8), 512, 0, stream>>>(Qb, Kb, Vt, Ob);
    // 6. GEMM2: out = O @ Wo (f32)  (256 blocks, 1 tile each)
    gemm256<1><<<256, 512, 0, stream>>>(
        Ob, wo_t, M, D, D, nullptr, nullptr, nullptr, (float*)d_out, 1.0f, 1);
}

// Round 23
// 445.591 us; speedup vs baseline: 1.6566x; 1.6566x over previous
//
#include <hip/hip_runtime.h>

typedef __attribute__((ext_vector_type(8))) short short8;
typedef __attribute__((ext_vector_type(4))) short short4v;
typedef __attribute__((ext_vector_type(4))) float f32x4;

__device__ inline short f2bf(float f) {
    union { float f; unsigned u; } v; v.f = f;
    unsigned r = v.u + 0x7fffu + ((v.u >> 16) & 1u);
    return (short)(r >> 16);
}

__device__ __forceinline__ void gload16(const short* g, short* l) {
    __builtin_amdgcn_global_load_lds(
        (const __attribute__((address_space(1))) unsigned int*)g,
        (__attribute__((address_space(3))) unsigned int*)l, 16, 0, 0);
}

// ---------------- elementwise f32 -> bf16 (16B/lane both ways) ----------------
__global__ __launch_bounds__(256) void cvt_f32_to_bf16(const float* __restrict__ in,
                                                       short* __restrict__ out, int n8) {
    int i = blockIdx.x * 256 + threadIdx.x;
    if (i >= n8) return;
    float4 a = ((const float4*)in)[i * 2];
    float4 b = ((const float4*)in)[i * 2 + 1];
    short8 o;
    o[0] = f2bf(a.x); o[1] = f2bf(a.y); o[2] = f2bf(a.z); o[3] = f2bf(a.w);
    o[4] = f2bf(b.x); o[5] = f2bf(b.y); o[6] = f2bf(b.z); o[7] = f2bf(b.w);
    ((short8*)out)[i] = o;
}

// ---------------- tiled transpose (R x C) f32 -> bf16 (C x R), vectorized ----------------
__global__ __launch_bounds__(256) void transpose_to_bf16(const float* __restrict__ in,
                                                         short* __restrict__ out,
                                                         int R, int C) {
    __shared__ short tile[64][68];
    int r0 = blockIdx.x * 64, c0 = blockIdx.y * 64;
    int tid = threadIdx.x;
#pragma unroll
    for (int i = 0; i < 4; i++) {
        int k = i * 256 + tid;
        int r = k >> 4, c4 = k & 15;
        float4 v = *(const float4*)(in + (size_t)(r0 + r) * C + c0 + c4 * 4);
        short4v s;
        s[0] = f2bf(v.x); s[1] = f2bf(v.y); s[2] = f2bf(v.z); s[3] = f2bf(v.w);
        *(short4v*)&tile[r][c4 * 4] = s;
    }
    __syncthreads();
#pragma unroll
    for (int i = 0; i < 2; i++) {
        int k = i * 256 + tid;
        int c = k >> 3, r8 = k & 7;
        short8 o;
#pragma unroll
        for (int j = 0; j < 8; j++) o[j] = tile[r8 * 8 + j][c];
        *(short8*)(out + (size_t)(c0 + c) * R + r0 + r8 * 8) = o;
    }
}

// ======== bf16 GEMM 256x256, BK=32, 4-buf depth-3, persistent (r21, unchanged) ====
template <int EPI>
__global__ __launch_bounds__(512) void gemm256(const short* __restrict__ A,
                                               const short* __restrict__ Bt,
                                               int M, int N, int K,
                                               short* __restrict__ O0, short* __restrict__ O1,
                                               short* __restrict__ O2, float* __restrict__ OF,
                                               float qscale, int gpb) {
    __shared__ short As[4][256 * 32];
    __shared__ short Bs[4][256 * 32];
    int tid = threadIdx.x, lane = tid & 63, wid = tid >> 6;
    int wr = wid >> 2, wc = wid & 3;
    int mtn = M >> 8;
    int band = mtn >> 3;
    int bid = blockIdx.x;
    int xcd = bid & 7;
    int kkstep = gridDim.x >> 3;
    int t15 = lane & 15, t4 = lane >> 4;
    int NT = K >> 5;
    int sg = (lane & 3) ^ ((lane >> 3) & 3);
    int srw = lane >> 2;
    int ce = t4 ^ ((t15 >> 1) & 3);

    for (int g = 0; g < gpb; g++) {
        int kk = (bid >> 3) + g * kkstep;
        int nt = kk / band, gmr = kk % band;
        int mt = xcd * band + gmr;
        int row0 = mt << 8, col0 = nt << 8;

        f32x4 acc[8][4];
#pragma unroll
        for (int m = 0; m < 8; m++)
#pragma unroll
            for (int n = 0; n < 4; n++) acc[m][n] = (f32x4){0.f, 0.f, 0.f, 0.f};

        auto stageA = [&](int t) {
            if (t >= NT) return;
            int kb = t << 5;
            short* dst = &As[t & 3][0];
#pragma unroll
            for (int i = 0; i < 2; i++) {
                int seg = wid * 2 + i;
                int row = seg * 16 + srw;
                gload16(A + (size_t)(row0 + row) * K + kb + sg * 8, dst + seg * 512);
            }
        };
        auto stageB = [&](int t) {
            if (t >= NT) return;
            int kb = t << 5;
            short* dst = &Bs[t & 3][0];
#pragma unroll
            for (int i = 0; i < 2; i++) {
                int seg = wid * 2 + i;
                int row = seg * 16 + srw;
                gload16(Bt + (size_t)(col0 + row) * K + kb + sg * 8, dst + seg * 512);
            }
        };

        stageA(0); stageB(0);
        stageA(1); stageB(1);
        stageA(2); stageB(2);
        asm volatile("s_waitcnt vmcnt(8)" ::: "memory");
        asm volatile("s_barrier" ::: "memory");

        for (int t = 0; t < NT; t++) {
            int bufi = t & 3;
            short8 af[8], bf[4];
#pragma unroll
            for (int m = 0; m < 8; m++) {
                int row = wr * 128 + m * 16 + t15;
                af[m] = *(short8*)(&As[bufi][row * 32 + ce * 8]);
            }
#pragma unroll
            for (int n = 0; n < 4; n++) {
                int row = wc * 64 + n * 16 + t15;
                bf[n] = *(short8*)(&Bs[bufi][row * 32 + ce * 8]);
            }
            stageA(t + 3); stageB(t + 3);

            __builtin_amdgcn_s_setprio(1);
#pragma unroll
            for (int m = 0; m < 8; m++)
#pragma unroll
                for (int n = 0; n < 4; n++)
                    acc[m][n] = __builtin_amdgcn_mfma_f32_16x16x32_bf16(af[m], bf[n], acc[m][n], 0, 0, 0);
            __builtin_amdgcn_s_setprio(0);

            if (t + 3 < NT)       asm volatile("s_waitcnt vmcnt(8)" ::: "memory");
            else if (t + 3 == NT) asm volatile("s_waitcnt vmcnt(4)" ::: "memory");
            else                  asm volatile("s_waitcnt vmcnt(0)" ::: "memory");
            asm volatile("s_barrier" ::: "memory");
        }

#pragma unroll
        for (int m = 0; m < 8; m++) {
#pragma unroll
            for (int n = 0; n < 4; n++) {
#pragma unroll
                for (int r = 0; r < 4; r++) {
                    float v = acc[m][n][r];
                    int gm2 = row0 + wr * 128 + m * 16 + t4 * 4 + r;
                    int gn = col0 + wc * 64 + n * 16 + t15;
                    if (EPI == 0) {
                        int part = gn >> 11, within = gn & 2047;
                        int h = within >> 7, dk = within & 127;
                        int bb = gm2 >> 11, s = gm2 & 2047;
                        int z = bb * 16 + h;
                        if (part == 0) O0[((size_t)z * 2048 + s) * 128 + dk] = f2bf(v * qscale);
                        else if (part == 1) O1[((size_t)z * 2048 + s) * 128 + dk] = f2bf(v);
                        else O2[((size_t)z * 128 + dk) * 2048 + s] = f2bf(v);  // V transposed
                    } else {
                        OF[(size_t)gm2 * N + gn] = v;
                    }
                }
            }
        }
    }
}

// ---------------- causal flash attention: 32 q-rows/wave, NO min-occupancy bound ----
// r22's __launch_bounds__(512,4) strangled the allocator to 64 VGPR -> 680MB spill
// (r7 lesson repeated). Plain (512): ~190 VGPR fits; LDS 80KB keeps 2 blocks/CU.
// Each kf/vf ds_read feeds TWO MFMAs (q-halves) -> per-q-row LDS traffic ~0.55x.
__global__ __launch_bounds__(512) void attn_fwd(const short* __restrict__ Q,
                                                const short* __restrict__ Kb,
                                                const short* __restrict__ Vt,
                                                short* __restrict__ O) {
    __shared__ short Kls[2][64 * 128];
    __shared__ short Vls[128 * 64];
    __shared__ __align__(16) short Pls[8][32 * 64];
    int tid = threadIdx.x, lane = tid & 63, wid = tid >> 6;
    int z = blockIdx.x, p = blockIdx.y;
    int t15 = lane & 15, t4 = lane >> 4;
    const short* Qh = Q + (size_t)z * 2048 * 128;
    const short* Kh = Kb + (size_t)z * 2048 * 128;
    const short* Vh = Vt + (size_t)z * 128 * 2048;
    int q0w = p * 256 + wid * 32;

    short8 qf[2][4];
#pragma unroll
    for (int h = 0; h < 2; h++) {
        const short* qrow = Qh + (size_t)(q0w + h * 16 + t15) * 128;
#pragma unroll
        for (int s = 0; s < 4; s++) qf[h][s] = *(const short8*)(qrow + s * 32 + t4 * 8);
    }

    f32x4 o0[8], o1[8];
#pragma unroll
    for (int st = 0; st < 8; st++) {
        o0[st] = (f32x4){0.f, 0.f, 0.f, 0.f};
        o1[st] = (f32x4){0.f, 0.f, 0.f, 0.f};
    }
    float m_s[2] = {-1e30f, -1e30f}, l_s[2] = {0.f, 0.f};

    auto stageK = [&](int t, int buf) {
#pragma unroll
        for (int i = 0; i < 2; i++) {
            int seg = wid * 2 + i;
            int row = seg * 4 + t4;
            int kl = (lane & 15) ^ (row & 7);
            gload16(Kh + (size_t)(t * 64 + row) * 128 + kl * 8, &Kls[buf][seg * 512]);
        }
    };
    auto stageV = [&](int t) {
#pragma unroll
        for (int i = 0; i < 2; i++) {
            int seg = wid * 2 + i;
            int row = seg * 8 + (lane >> 3);
            int kl = (lane & 7) ^ (row & 7);
            gload16(Vh + (size_t)row * 2048 + t * 64 + kl * 8, &Vls[seg * 512]);
        }
    };

    int nt = 4 * p + 4;
    stageK(0, 0);
    __syncthreads();

    int t15l = t15 & 7;

    for (int t = 0; t < nt; t++) {
        int buf = t & 1;
        stageV(t);
        if (t + 1 < nt) stageK(t + 1, buf ^ 1);
        bool active = (t * 64 <= q0w + 15);

        if (active) {
            f32x4 sc0[4], sc1[4];
#pragma unroll
            for (int c = 0; c < 4; c++) {
                sc0[c] = (f32x4){0.f, 0.f, 0.f, 0.f};
                sc1[c] = (f32x4){0.f, 0.f, 0.f, 0.f};
            }
#pragma unroll
            for (int c = 0; c < 4; c++) {
#pragma unroll
                for (int s = 0; s < 4; s++) {
                    int row = c * 16 + t15;
                    int ck = (s * 4 + t4) ^ (row & 7);
                    short8 kf = *(short8*)(&Kls[buf][row * 128 + ck * 8]);
                    sc0[c] = __builtin_amdgcn_mfma_f32_16x16x32_bf16(kf, qf[0][s], sc0[c], 0, 0, 0);
                    sc1[c] = __builtin_amdgcn_mfma_f32_16x16x32_bf16(kf, qf[1][s], sc1[c], 0, 0, 0);
                }
            }

            bool diag = (t * 64 + 63 > q0w);

            // ---- half 0 ----
            {
                f32x4* sc = sc0;
                if (diag) {
                    int qq = q0w + t15;
#pragma unroll
                    for (int c = 0; c < 4; c++)
#pragma unroll
                        for (int r = 0; r < 4; r++) {
                            int kv = t * 64 + c * 16 + t4 * 4 + r;
                            if (kv > qq) sc[c][r] = -1e30f;
                        }
                }
                float tm = fmaxf(fmaxf(fmaxf(sc[0][0], sc[0][1]), fmaxf(sc[0][2], sc[0][3])),
                                 fmaxf(fmaxf(sc[1][0], sc[1][1]), fmaxf(sc[1][2], sc[1][3])));
                tm = fmaxf(tm, fmaxf(fmaxf(fmaxf(sc[2][0], sc[2][1]), fmaxf(sc[2][2], sc[2][3])),
                                     fmaxf(fmaxf(sc[3][0], sc[3][1]), fmaxf(sc[3][2], sc[3][3]))));
                bool need = (tm > m_s[0] + 8.f);
                if (__any(need)) {
                    tm = fmaxf(tm, __shfl_xor(tm, 16));
                    tm = fmaxf(tm, __shfl_xor(tm, 32));
                    float mn = fmaxf(m_s[0], tm);
                    float scf = exp2f(m_s[0] - mn);
                    m_s[0] = mn;
                    l_s[0] *= scf;
                    float sr0 = __shfl(scf, t4 * 4 + 0);
                    float sr1 = __shfl(scf, t4 * 4 + 1);
                    float sr2 = __shfl(scf, t4 * 4 + 2);
                    float sr3 = __shfl(scf, t4 * 4 + 3);
#pragma unroll
                    for (int st = 0; st < 8; st++) {
                        o0[st][0] *= sr0; o0[st][1] *= sr1;
                        o0[st][2] *= sr2; o0[st][3] *= sr3;
                    }
                }
#pragma unroll
                for (int c = 0; c < 4; c++) {
                    float p0 = exp2f(sc[c][0] - m_s[0]);
                    float p1 = exp2f(sc[c][1] - m_s[0]);
                    float p2 = exp2f(sc[c][2] - m_s[0]);
                    float p3 = exp2f(sc[c][3] - m_s[0]);
                    l_s[0] += (p0 + p1) + (p2 + p3);
                    unsigned u0, u1;
                    asm("v_cvt_pk_bf16_f32 %0, %1, %2" : "=v"(u0) : "v"(p0), "v"(p1));
                    asm("v_cvt_pk_bf16_f32 %0, %1, %2" : "=v"(u1) : "v"(p2), "v"(p3));
                    int ch = (c * 2 + (t4 >> 1)) ^ t15l;
                    uint2 uu; uu.x = u0; uu.y = u1;
                    *(uint2*)((char*)&Pls[wid][0] + t15 * 128 + ch * 16 + (t4 & 1) * 8) = uu;
                }
            }
            // ---- half 1 ----
            {
                f32x4* sc = sc1;
                if (diag) {
                    int qq = q0w + 16 + t15;
#pragma unroll
                    for (int c = 0; c < 4; c++)
#pragma unroll
                        for (int r = 0; r < 4; r++) {
                            int kv = t * 64 + c * 16 + t4 * 4 + r;
                            if (kv > qq) sc[c][r] = -1e30f;
                        }
                }
                float tm = fmaxf(fmaxf(fmaxf(sc[0][0], sc[0][1]), fmaxf(sc[0][2], sc[0][3])),
                                 fmaxf(fmaxf(sc[1][0], sc[1][1]), fmaxf(sc[1][2], sc[1][3])));
                tm = fmaxf(tm, fmaxf(fmaxf(fmaxf(sc[2][0], sc[2][1]), fmaxf(sc[2][2], sc[2][3])),
                                     fmaxf(fmaxf(sc[3][0], sc[3][1]), fmaxf(sc[3][2], sc[3][3]))));
                bool need = (tm > m_s[1] + 8.f);
                if (__any(need)) {
                    tm = fmaxf(tm, __shfl_xor(tm, 16));
                    tm = fmaxf(tm, __shfl_xor(tm, 32));
                    float mn = fmaxf(m_s[1], tm);
                    float scf = exp2f(m_s[1] - mn);
                    m_s[1] = mn;
                    l_s[1] *= scf;
                    float sr0 = __shfl(scf, t4 * 4 + 0);
                    float sr1 = __shfl(scf, t4 * 4 + 1);
                    float sr2 = __shfl(scf, t4 * 4 + 2);
                    float sr3 = __shfl(scf, t4 * 4 + 3);
#pragma unroll
                    for (int st = 0; st < 8; st++) {
                        o1[st][0] *= sr0; o1[st][1] *= sr1;
                        o1[st][2] *= sr2; o1[st][3] *= sr3;
                    }
                }
#pragma unroll
                for (int c = 0; c < 4; c++) {
                    float p0 = exp2f(sc[c][0] - m_s[1]);
                    float p1 = exp2f(sc[c][1] - m_s[1]);
                    float p2 = exp2f(sc[c][2] - m_s[1]);
                    float p3 = exp2f(sc[c][3] - m_s[1]);
                    l_s[1] += (p0 + p1) + (p2 + p3);
                    unsigned u0, u1;
                    asm("v_cvt_pk_bf16_f32 %0, %1, %2" : "=v"(u0) : "v"(p0), "v"(p1));
                    asm("v_cvt_pk_bf16_f32 %0, %1, %2" : "=v"(u1) : "v"(p2), "v"(p3));
                    int ch = (c * 2 + (t4 >> 1)) ^ t15l;
                    uint2 uu; uu.x = u0; uu.y = u1;
                    *(uint2*)((char*)&Pls[wid][0] + (16 + t15) * 128 + ch * 16 + (t4 & 1) * 8) = uu;
                }
            }
        }

        if (t + 1 < nt) asm volatile("s_waitcnt vmcnt(2)" ::: "memory");
        else            asm volatile("s_waitcnt vmcnt(0)" ::: "memory");
        __builtin_amdgcn_s_barrier();

        if (active) {
            short8 pa0[2], pa1[2];
#pragma unroll
            for (int s2 = 0; s2 < 2; s2++) {
                int ch2 = (s2 * 4 + t4) ^ t15l;
                pa0[s2] = *(short8*)((char*)&Pls[wid][0] + t15 * 128 + ch2 * 16);
                pa1[s2] = *(short8*)((char*)&Pls[wid][0] + (16 + t15) * 128 + ch2 * 16);
            }
#pragma unroll
            for (int st = 0; st < 8; st++) {
#pragma unroll
                for (int s2 = 0; s2 < 2; s2++) {
                    int row = st * 16 + t15;
                    int ck = (s2 * 4 + t4) ^ (row & 7);
                    short8 vf = *(short8*)(&Vls[row * 64 + ck * 8]);
                    o0[st] = __builtin_amdgcn_mfma_f32_16x16x32_bf16(pa0[s2], vf, o0[st], 0, 0, 0);
                    o1[st] = __builtin_amdgcn_mfma_f32_16x16x32_bf16(pa1[s2], vf, o1[st], 0, 0, 0);
                }
            }
        }

        asm volatile("s_waitcnt vmcnt(0)" ::: "memory");
        __builtin_amdgcn_s_barrier();
    }

    int b = z >> 4, hh = z & 15;
#pragma unroll
    for (int h = 0; h < 2; h++) {
        float ls = l_s[h];
        ls += __shfl_xor(ls, 16);
        ls += __shfl_xor(ls, 32);
        float lr0 = __shfl(ls, t4 * 4 + 0);
        float lr1 = __shfl(ls, t4 * 4 + 1);
        float lr2 = __shfl(ls, t4 * 4 + 2);
        float lr3 = __shfl(ls, t4 * 4 + 3);
        float lr[4] = {lr0, lr1, lr2, lr3};
        f32x4* o = (h == 0) ? o0 : o1;
#pragma unroll
        for (int st = 0; st < 8; st++)
#pragma unroll
            for (int r = 0; r < 4; r++) {
                int s = q0w + h * 16 + t4 * 4 + r;
                float val = o[st][r] / lr[r];
                O[((size_t)b * 2048 + s) * 2048 + hh * 128 + st * 16 + t15] = f2bf(val);
            }
    }
}

extern "C" void kernel_launch(void* const* d_in, const int* in_sizes, int n_in,
                              void* d_out, int out_size, void* d_ws, size_t ws_size,
                              hipStream_t stream) {
    const float* x = (const float*)d_in[0];      // (4,2048,2048)
    const float* Wqkv = (const float*)d_in[1];   // (2048,6144)
    const float* Wo = (const float*)d_in[2];     // (2048,2048)

    const int B = 4, S = 2048, D = 2048, DK = 128;
    const int M = B * S;          // 8192
    const int N1 = 3 * D;         // 6144
    (void)in_sizes; (void)n_in; (void)out_size; (void)ws_size;

    char* ws = (char*)d_ws;
    size_t off = 0;
    short* x_bf = (short*)(ws + off);   off += (size_t)M * D * 2;
    short* wqkv_t = (short*)(ws + off); off += (size_t)N1 * D * 2;
    short* wo_t = (short*)(ws + off);   off += (size_t)D * D * 2;
    short* Qb = (short*)(ws + off);     off += (size_t)64 * S * DK * 2;
    short* Kb = (short*)(ws + off);     off += (size_t)64 * S * DK * 2;
    short* Vt = (short*)(ws + off);     off += (size_t)64 * S * DK * 2;
    short* Ob = (short*)(ws + off);     off += (size_t)M * D * 2;

    // 1. x -> bf16 (16B/lane)
    cvt_f32_to_bf16<<<(M * D / 8 + 255) / 256, 256, 0, stream>>>(x, x_bf, M * D / 8);
    // 2. Wqkv^T -> bf16 (N1 x D), vectorized
    transpose_to_bf16<<<dim3(D / 64, N1 / 64, 1), 256, 0, stream>>>(Wqkv, wqkv_t, D, N1);
    // 3. Wo^T -> bf16 (D x D), vectorized
    transpose_to_bf16<<<dim3(D / 64, D / 64, 1), 256, 0, stream>>>(Wo, wo_t, D, D);
    // 4. GEMM1: qkv = x @ Wqkv -> Q(scaled 1/(sqrt(128)ln2))/K/V^T  (persistent, 256 x 3)
    gemm256<0><<<256, 512, 0, stream>>>(
        x_bf, wqkv_t, M, N1, D, Qb, Kb, Vt, nullptr, 0.12751743553366927f, 3);
    // 5. attention (256-row panels, 32 q-rows/wave, shared K/V reads, no min-bound)
    attn_fwd<<<dim3(64, 8), 512, 0, stream>>>(Qb, Kb, Vt, Ob);
    // 6. GEMM2: out = O @ Wo (f32)  (256 blocks, 1 tile each)
    gemm256<1><<<256, 512, 0, stream>>>(
        Ob, wo_t, M, D, D, nullptr, nullptr, nullptr, (float*)d_out, 1.0f, 1);
}

// Round 24
// 435.928 us; speedup vs baseline: 1.6933x; 1.0222x over previous
//
#include <hip/hip_runtime.h>

typedef __attribute__((ext_vector_type(8))) short short8;
typedef __attribute__((ext_vector_type(4))) short short4v;
typedef __attribute__((ext_vector_type(4))) float f32x4;

__device__ inline short f2bf(float f) {
    union { float f; unsigned u; } v; v.f = f;
    unsigned r = v.u + 0x7fffu + ((v.u >> 16) & 1u);
    return (short)(r >> 16);
}

__device__ __forceinline__ void gload16(const short* g, short* l) {
    __builtin_amdgcn_global_load_lds(
        (const __attribute__((address_space(1))) unsigned int*)g,
        (__attribute__((address_space(3))) unsigned int*)l, 16, 0, 0);
}

// ---------------- elementwise f32 -> bf16 ----------------
__global__ __launch_bounds__(256) void cvt_f32_to_bf16(const float* __restrict__ in,
                                                       short* __restrict__ out, int n4) {
    int i = blockIdx.x * 256 + threadIdx.x;
    if (i >= n4) return;
    float4 v = ((const float4*)in)[i];
    short4v o;
    o[0] = f2bf(v.x); o[1] = f2bf(v.y); o[2] = f2bf(v.z); o[3] = f2bf(v.w);
    ((short4v*)out)[i] = o;
}

// ---------------- tiled transpose (R x C) f32 -> bf16 (C x R) ----------------
__global__ __launch_bounds__(256) void transpose_to_bf16(const float* __restrict__ in,
                                                         short* __restrict__ out,
                                                         int R, int C) {
    __shared__ short tile[64][66];
    int r0 = blockIdx.x * 64, c0 = blockIdx.y * 64;
    int tid = threadIdx.x;
#pragma unroll
    for (int i = 0; i < 16; i++) {
        int idx = i * 256 + tid;
        int r = idx >> 6, c = idx & 63;
        tile[r][c] = f2bf(in[(size_t)(r0 + r) * C + (c0 + c)]);
    }
    __syncthreads();
#pragma unroll
    for (int i = 0; i < 16; i++) {
        int idx = i * 256 + tid;
        int c = idx >> 6, r = idx & 63;
        out[(size_t)(c0 + c) * R + (r0 + r)] = tile[r][c];
    }
}

// ======== bf16 GEMM 256x256, BK=32, 4-buf depth-3 (r16/r20 proven) ====
template <int EPI>
__global__ __launch_bounds__(512) void gemm256(const short* __restrict__ A,
                                               const short* __restrict__ Bt,
                                               int M, int N, int K,
                                               short* __restrict__ O0, short* __restrict__ O1,
                                               short* __restrict__ O2, float* __restrict__ OF,
                                               float qscale) {
    __shared__ short As[4][256 * 32];
    __shared__ short Bs[4][256 * 32];
    int tid = threadIdx.x, lane = tid & 63, wid = tid >> 6;
    int wr = wid >> 2, wc = wid & 3;
    int mtn = M >> 8;
    int band = mtn >> 3;
    int bid = blockIdx.x;
    int xcd = bid & 7, kk = bid >> 3;
    int nt = kk / band, gmr = kk % band;
    int mt = xcd * band + gmr;
    int row0 = mt << 8, col0 = nt << 8;
    int t15 = lane & 15, t4 = lane >> 4;
    int NT = K >> 5;

    f32x4 acc[8][4];
#pragma unroll
    for (int m = 0; m < 8; m++)
#pragma unroll
        for (int n = 0; n < 4; n++) acc[m][n] = (f32x4){0.f, 0.f, 0.f, 0.f};

    int sg = (lane & 3) ^ ((lane >> 3) & 3);
    int srw = lane >> 2;
    int ce = t4 ^ ((t15 >> 1) & 3);

    auto stageA = [&](int t) {
        if (t >= NT) return;
        int kb = t << 5;
        short* dst = &As[t & 3][0];
#pragma unroll
        for (int i = 0; i < 2; i++) {
            int seg = wid * 2 + i;
            int row = seg * 16 + srw;
            gload16(A + (size_t)(row0 + row) * K + kb + sg * 8, dst + seg * 512);
        }
    };
    auto stageB = [&](int t) {
        if (t >= NT) return;
        int kb = t << 5;
        short* dst = &Bs[t & 3][0];
#pragma unroll
        for (int i = 0; i < 2; i++) {
            int seg = wid * 2 + i;
            int row = seg * 16 + srw;
            gload16(Bt + (size_t)(col0 + row) * K + kb + sg * 8, dst + seg * 512);
        }
    };

    stageA(0); stageB(0);
    stageA(1); stageB(1);
    stageA(2); stageB(2);
    asm volatile("s_waitcnt vmcnt(8)" ::: "memory");
    asm volatile("s_barrier" ::: "memory");

    for (int t = 0; t < NT; t++) {
        int bufi = t & 3;
        short8 af[8], bf[4];
#pragma unroll
        for (int m = 0; m < 8; m++) {
            int row = wr * 128 + m * 16 + t15;
            af[m] = *(short8*)(&As[bufi][row * 32 + ce * 8]);
        }
#pragma unroll
        for (int n = 0; n < 4; n++) {
            int row = wc * 64 + n * 16 + t15;
            bf[n] = *(short8*)(&Bs[bufi][row * 32 + ce * 8]);
        }
        stageA(t + 3); stageB(t + 3);

        __builtin_amdgcn_s_setprio(1);
#pragma unroll
        for (int m = 0; m < 8; m++)
#pragma unroll
            for (int n = 0; n < 4; n++)
                acc[m][n] = __builtin_amdgcn_mfma_f32_16x16x32_bf16(af[m], bf[n], acc[m][n], 0, 0, 0);
        __builtin_amdgcn_s_setprio(0);

        if (t + 3 < NT)       asm volatile("s_waitcnt vmcnt(8)" ::: "memory");
        else if (t + 3 == NT) asm volatile("s_waitcnt vmcnt(4)" ::: "memory");
        else                  asm volatile("s_waitcnt vmcnt(0)" ::: "memory");
        asm volatile("s_barrier" ::: "memory");
    }

#pragma unroll
    for (int m = 0; m < 8; m++) {
#pragma unroll
        for (int n = 0; n < 4; n++) {
#pragma unroll
            for (int r = 0; r < 4; r++) {
                float v = acc[m][n][r];
                int gm2 = row0 + wr * 128 + m * 16 + t4 * 4 + r;
                int gn = col0 + wc * 64 + n * 16 + t15;
                if (EPI == 0) {
                    int part = gn >> 11, within = gn & 2047;
                    int h = within >> 7, dk = within & 127;
                    int bb = gm2 >> 11, s = gm2 & 2047;
                    int z = bb * 16 + h;
                    if (part == 0) O0[((size_t)z * 2048 + s) * 128 + dk] = f2bf(v * qscale);
                    else if (part == 1) O1[((size_t)z * 2048 + s) * 128 + dk] = f2bf(v);
                    else O2[((size_t)z * 128 + dk) * 2048 + s] = f2bf(v);  // V transposed
                } else {
                    OF[(size_t)gm2 * N + gn] = v;
                }
            }
        }
    }
}

// ---------------- causal flash attention: paired panels + counted-vmcnt (r20 proven) ----
__global__ __launch_bounds__(512, 4) void attn_fwd(const short* __restrict__ Q,
                                                   const short* __restrict__ Kb,
                                                   const short* __restrict__ Vt,
                                                   short* __restrict__ O) {
    __shared__ short Kls[2][64 * 128];
    __shared__ short Vls[128 * 64];
    __shared__ __align__(16) short Pls[8][16 * 64];
    int tid = threadIdx.x, lane = tid & 63, wid = tid >> 6;
    int bx = blockIdx.x, z = blockIdx.y;
    int pr = bx >> 1, hh = bx & 1;
    int qpan = (wid < 4) ? pr : (15 - pr);
    int t15 = lane & 15, t4 = lane >> 4;
    const short* Qh = Q + (size_t)z * 2048 * 128;
    const short* Kh = Kb + (size_t)z * 2048 * 128;
    const short* Vh = Vt + (size_t)z * 128 * 2048;
    int q0w = qpan * 128 + hh * 64 + (wid & 3) * 16;

    short8 qf[4];
    {
        const short* qrow = Qh + (size_t)(q0w + t15) * 128;
#pragma unroll
        for (int s = 0; s < 4; s++) qf[s] = *(const short8*)(qrow + s * 32 + t4 * 8);
    }

    f32x4 o[8];
#pragma unroll
    for (int st = 0; st < 8; st++) o[st] = (f32x4){0.f, 0.f, 0.f, 0.f};
    float m_s = -1e30f, l_s = 0.f;

    auto stageK = [&](int t, int buf) {
#pragma unroll
        for (int i = 0; i < 2; i++) {
            int seg = wid * 2 + i;
            int row = seg * 4 + t4;
            int kl = (lane & 15) ^ (row & 7);
            gload16(Kh + (size_t)(t * 64 + row) * 128 + kl * 8, &Kls[buf][seg * 512]);
        }
    };
    auto stageV = [&](int t) {
#pragma unroll
        for (int i = 0; i < 2; i++) {
            int seg = wid * 2 + i;
            int row = seg * 8 + (lane >> 3);
            int kl = (lane & 7) ^ (row & 7);
            gload16(Vh + (size_t)row * 2048 + t * 64 + kl * 8, &Vls[seg * 512]);
        }
    };

    int nt = 2 * (15 - pr) + 2;
    stageK(0, 0);
    __syncthreads();

    for (int t = 0; t < nt; t++) {
        int buf = t & 1;
        stageV(t);
        if (t + 1 < nt) stageK(t + 1, buf ^ 1);
        bool active = (t * 64 <= q0w + 15);

        if (active) {
            f32x4 sc[4];
#pragma unroll
            for (int c = 0; c < 4; c++) {
                sc[c] = (f32x4){0.f, 0.f, 0.f, 0.f};
#pragma unroll
                for (int s = 0; s < 4; s++) {
                    int row = c * 16 + t15;
                    int ck = (s * 4 + t4) ^ (row & 7);
                    short8 kf = *(short8*)(&Kls[buf][row * 128 + ck * 8]);
                    sc[c] = __builtin_amdgcn_mfma_f32_16x16x32_bf16(kf, qf[s], sc[c], 0, 0, 0);
                }
            }

            if (t * 64 + 63 > q0w) {
                int qq = q0w + t15;
#pragma unroll
                for (int c = 0; c < 4; c++)
#pragma unroll
                    for (int r = 0; r < 4; r++) {
                        int kv = t * 64 + c * 16 + t4 * 4 + r;
                        if (kv > qq) sc[c][r] = -1e30f;
                    }
            }

            float tm = fmaxf(fmaxf(fmaxf(sc[0][0], sc[0][1]), fmaxf(sc[0][2], sc[0][3])),
                             fmaxf(fmaxf(sc[1][0], sc[1][1]), fmaxf(sc[1][2], sc[1][3])));
            tm = fmaxf(tm, fmaxf(fmaxf(fmaxf(sc[2][0], sc[2][1]), fmaxf(sc[2][2], sc[2][3])),
                                 fmaxf(fmaxf(sc[3][0], sc[3][1]), fmaxf(sc[3][2], sc[3][3]))));
            bool need = (tm > m_s + 8.f);
            if (__any(need)) {
                tm = fmaxf(tm, __shfl_xor(tm, 16));
                tm = fmaxf(tm, __shfl_xor(tm, 32));
                float mn = fmaxf(m_s, tm);
                float scf = exp2f(m_s - mn);
                m_s = mn;
                l_s *= scf;
                float sr0 = __shfl(scf, t4 * 4 + 0);
                float sr1 = __shfl(scf, t4 * 4 + 1);
                float sr2 = __shfl(scf, t4 * 4 + 2);
                float sr3 = __shfl(scf, t4 * 4 + 3);
#pragma unroll
                for (int st = 0; st < 8; st++) {
                    o[st][0] *= sr0; o[st][1] *= sr1;
                    o[st][2] *= sr2; o[st][3] *= sr3;
                }
            }
            int t15l = t15 & 7;
#pragma unroll
            for (int c = 0; c < 4; c++) {
                float p0 = exp2f(sc[c][0] - m_s);
                float p1 = exp2f(sc[c][1] - m_s);
                float p2 = exp2f(sc[c][2] - m_s);
                float p3 = exp2f(sc[c][3] - m_s);
                l_s += (p0 + p1) + (p2 + p3);
                unsigned u0, u1;
                asm("v_cvt_pk_bf16_f32 %0, %1, %2" : "=v"(u0) : "v"(p0), "v"(p1));
                asm("v_cvt_pk_bf16_f32 %0, %1, %2" : "=v"(u1) : "v"(p2), "v"(p3));
                int ch = (c * 2 + (t4 >> 1)) ^ t15l;
                uint2 uu; uu.x = u0; uu.y = u1;
                *(uint2*)((char*)&Pls[wid][0] + t15 * 128 + ch * 16 + (t4 & 1) * 8) = uu;
            }
        }

        if (t + 1 < nt) asm volatile("s_waitcnt vmcnt(2)" ::: "memory");
        else            asm volatile("s_waitcnt vmcnt(0)" ::: "memory");
        __builtin_amdgcn_s_barrier();

        if (active) {
            short8 pa[2];
#pragma unroll
            for (int s2 = 0; s2 < 2; s2++) {
                int ch2 = (s2 * 4 + t4) ^ (t15 & 7);
                pa[s2] = *(short8*)((char*)&Pls[wid][0] + t15 * 128 + ch2 * 16);
            }
#pragma unroll
            for (int st = 0; st < 8; st++) {
#pragma unroll
                for (int s2 = 0; s2 < 2; s2++) {
                    int row = st * 16 + t15;
                    int ck = (s2 * 4 + t4) ^ (row & 7);
                    short8 vf = *(short8*)(&Vls[row * 64 + ck * 8]);
                    o[st] = __builtin_amdgcn_mfma_f32_16x16x32_bf16(pa[s2], vf, o[st], 0, 0, 0);
                }
            }
        }

        asm volatile("s_waitcnt vmcnt(0)" ::: "memory");
        __builtin_amdgcn_s_barrier();
    }

    l_s += __shfl_xor(l_s, 16);
    l_s += __shfl_xor(l_s, 32);
    float lr0 = __shfl(l_s, t4 * 4 + 0);
    float lr1 = __shfl(l_s, t4 * 4 + 1);
    float lr2 = __shfl(l_s, t4 * 4 + 2);
    float lr3 = __shfl(l_s, t4 * 4 + 3);
    float lr[4] = {lr0, lr1, lr2, lr3};

    int b = z >> 4, h = z & 15;
#pragma unroll
    for (int st = 0; st < 8; st++)
#pragma unroll
        for (int r = 0; r < 4; r++) {
            int s = q0w + t4 * 4 + r;
            float val = o[st][r] / lr[r];
            O[((size_t)b * 2048 + s) * 2048 + h * 128 + st * 16 + t15] = f2bf(val);
        }
}

extern "C" void kernel_launch(void* const* d_in, const int* in_sizes, int n_in,
                              void* d_out, int out_size, void* d_ws, size_t ws_size,
                              hipStream_t stream) {
    const float* x = (const float*)d_in[0];      // (4,2048,2048)
    const float* Wqkv = (const float*)d_in[1];   // (2048,6144)
    const float* Wo = (const float*)d_in[2];     // (2048,2048)

    const int B = 4, S = 2048, D = 2048, DK = 128;
    const int M = B * S;          // 8192
    const int N1 = 3 * D;         // 6144
    (void)in_sizes; (void)n_in; (void)out_size; (void)ws_size;

    char* ws = (char*)d_ws;
    size_t off = 0;
    short* x_bf = (short*)(ws + off);   off += (size_t)M * D * 2;
    short* wqkv_t = (short*)(ws + off); off += (size_t)N1 * D * 2;
    short* wo_t = (short*)(ws + off);   off += (size_t)D * D * 2;
    short* Qb = (short*)(ws + off);     off += (size_t)64 * S * DK * 2;
    short* Kb = (short*)(ws + off);     off += (size_t)64 * S * DK * 2;
    short* Vt = (short*)(ws + off);     off += (size_t)64 * S * DK * 2;
    short* Ob = (short*)(ws + off);     off += (size_t)M * D * 2;

    // 1. x -> bf16
    cvt_f32_to_bf16<<<(M * D / 4 + 255) / 256, 256, 0, stream>>>(x, x_bf, M * D / 4);
    // 2. Wqkv^T -> bf16 (N1 x D)
    transpose_to_bf16<<<dim3(D / 64, N1 / 64, 1), 256, 0, stream>>>(Wqkv, wqkv_t, D, N1);
    // 3. Wo^T -> bf16 (D x D)
    transpose_to_bf16<<<dim3(D / 64, D / 64, 1), 256, 0, stream>>>(Wo, wo_t, D, D);
    // 4. GEMM1: qkv = x @ Wqkv -> Q(scaled 1/(sqrt(128)ln2))/K/V^T  (256² depth-3, 768 blocks)
    gemm256<0><<<(M / 256) * (N1 / 256), 512, 0, stream>>>(
        x_bf, wqkv_t, M, N1, D, Qb, Kb, Vt, nullptr, 0.12751743553366927f);
    // 5. attention (paired panels + counted-vmcnt barriers)
    attn_fwd<<<dim3(16, 64), 512, 0, stream>>>(Qb, Kb, Vt, Ob);
    // 6. GEMM2: out = O @ Wo (f32)   (256² depth-3, 256 blocks)
    gemm256<1><<<(M / 256) * (D / 256), 512, 0, stream>>>(
        Ob, wo_t, M, D, D, nullptr, nullptr, nullptr, (float*)d_out, 1.0f);
}